// Round 9
// baseline (207.311 us; speedup 1.0000x reference)
//
#include <hip/hip_runtime.h>
#include <hip/hip_bf16.h>

#define N_ROWS 16384
#define D_COLS 2048
#define NUM_LABELS 1024
#define NUM_CAMS 8
#define NUM_SEG (NUM_LABELS * NUM_CAMS)   // 8192
#define MAXPER 64                          // list capacity per segment
#define GSEG 8                             // segments per block
#define NUM_GROUPS (NUM_SEG / GSEG)        // 1024
#define NUM_BLOCKS (NUM_GROUPS * 2)        // 2048 blocks: (group, half) -> 8/CU, ALL resident
#define FAST_R 4                           // register-cached rows/segment (P(cnt>4)~5%)
#define IDX_LDS 12                         // indices staged in LDS per segment
#define F4_PER_ROW (D_COLS / 4)            // 512 float4 per row

// ---------------- kernel 1: build per-segment row lists ----------------
__global__ void build_lists_kernel(const int* __restrict__ labels,
                                   const int* __restrict__ cams,
                                   int* __restrict__ counts,
                                   int* __restrict__ lists) {
    int i = blockIdx.x * blockDim.x + threadIdx.x;
    if (i < N_ROWS) {
        int seg = labels[i] * NUM_CAMS + cams[i];
        int pos = atomicAdd(&counts[seg], 1);
        if (pos < MAXPER) lists[seg * MAXPER + pos] = i;
    }
}

__device__ __forceinline__ float smooth_l1(float d) {
    float ad = fabsf(d);
    return ad < 1.0f ? 0.5f * d * d : ad - 0.5f;
}

// ---------------- kernel 2: one block per (8 segments, column-half) ----------------
// 2048 blocks = 8/CU all resident. Depth-2 software pipeline over segments:
// while consuming segment s (sum/mean/loss from registers), segment s+1's
// 4 row loads are already in flight -> 2 HBM latencies hidden per wave.
__global__ __launch_bounds__(256, 8) void group_loss_kernel(const float* __restrict__ feats,
                                                            const int* __restrict__ counts,
                                                            const int* __restrict__ lists,
                                                            float* __restrict__ partials) {
    int bid  = blockIdx.x;
    int grp  = bid >> 1;
    int half = bid & 1;
    int tid  = threadIdx.x;
    int seg0 = grp * GSEG;

    __shared__ int   scnt[GSEG];
    __shared__ int   sidx[GSEG][IDX_LDS];
    __shared__ float wsum[4];

    // phase 0: metadata -> LDS (threads 0..7 counts, 8..103 indices)
    if (tid < GSEG) {
        scnt[tid] = counts[seg0 + tid];
    } else if (tid < GSEG + GSEG * IDX_LDS) {
        int j = tid - GSEG;
        int s = j / IDX_LDS;
        int r = j - s * IDX_LDS;
        sidx[s][r] = lists[(seg0 + s) * MAXPER + r];  // poison slots masked by cnt
    }
    __syncthreads();

    const float4* base = (const float4*)feats + (half * 256 + tid);
    float loss = 0.0f;

    // load first min(cnt,4) rows of segment s into v[]; returns cnt
    auto load4 = [&](float4* v, int s) -> int {
        int cnt  = scnt[s];
        int rows = cnt < FAST_R ? cnt : FAST_R;
#pragma unroll
        for (int r = 0; r < FAST_R; ++r) {
            v[r] = make_float4(0.f, 0.f, 0.f, 0.f);
            if (r < rows)
                v[r] = base[(size_t)sidx[s][r] * F4_PER_ROW];
        }
        return cnt;
    };

    // consume one segment: sum (4 slots + rare streamed tail), mean, loss
    auto consume = [&](const float4* v, int s, int cnt) {
        int rows = cnt < FAST_R ? cnt : FAST_R;
        float mx = 0.f, my = 0.f, mz = 0.f, mw = 0.f;
#pragma unroll
        for (int r = 0; r < FAST_R; ++r) {
            mx += v[r].x; my += v[r].y; mz += v[r].z; mw += v[r].w;
        }
        if (cnt > FAST_R) {                       // rare tail: stream-add
            for (int r = FAST_R; r < cnt && r < IDX_LDS; ++r) {
                float4 a = base[(size_t)sidx[s][r] * F4_PER_ROW];
                mx += a.x; my += a.y; mz += a.z; mw += a.w;
            }
            for (int r = IDX_LDS; r < cnt && r < MAXPER; ++r) {
                float4 a = base[(size_t)lists[(seg0 + s) * MAXPER + r] * F4_PER_ROW];
                mx += a.x; my += a.y; mz += a.z; mw += a.w;
            }
        }
        float inv = 1.0f / (float)(cnt > 0 ? cnt : 1);
        mx *= inv; my *= inv; mz *= inv; mw *= inv;

#pragma unroll
        for (int r = 0; r < FAST_R; ++r) {
            if (r < rows)
                loss += smooth_l1(v[r].x - mx) + smooth_l1(v[r].y - my)
                      + smooth_l1(v[r].z - mz) + smooth_l1(v[r].w - mw);
        }
        if (cnt > FAST_R) {                       // rare tail: re-stream (L2-hot)
            for (int r = FAST_R; r < cnt && r < IDX_LDS; ++r) {
                float4 a = base[(size_t)sidx[s][r] * F4_PER_ROW];
                loss += smooth_l1(a.x - mx) + smooth_l1(a.y - my)
                      + smooth_l1(a.z - mz) + smooth_l1(a.w - mw);
            }
            for (int r = IDX_LDS; r < cnt && r < MAXPER; ++r) {
                float4 a = base[(size_t)lists[(seg0 + s) * MAXPER + r] * F4_PER_ROW];
                loss += smooth_l1(a.x - mx) + smooth_l1(a.y - my)
                      + smooth_l1(a.z - mz) + smooth_l1(a.w - mw);
            }
        }
    };

    // depth-2 pipeline: ping-pong register buffers, GSEG even
    float4 va[FAST_R], vb[FAST_R];
    int ca = load4(va, 0);
#pragma unroll 1
    for (int s = 0; s < GSEG; s += 2) {
        int cb = load4(vb, s + 1);                // in flight while consuming va
        consume(va, s, ca);
        if (s + 2 < GSEG)
            ca = load4(va, s + 2);                // in flight while consuming vb
        consume(vb, s + 1, cb);
    }

    // block reduction: wave64 shuffle then LDS across 4 waves
    for (int o = 32; o > 0; o >>= 1)
        loss += __shfl_down(loss, o, 64);

    int lane = tid & 63;
    int wid  = tid >> 6;
    if (lane == 0) wsum[wid] = loss;
    __syncthreads();
    if (tid == 0)
        partials[bid] = wsum[0] + wsum[1] + wsum[2] + wsum[3];
}

// ---------------- kernel 3: reduce partials -> scalar loss ----------------
__global__ __launch_bounds__(256) void reduce_kernel(const float* __restrict__ partials,
                                                     float* __restrict__ out) {
    int tid = threadIdx.x;
    float s = 0.0f;
    for (int i = tid; i < NUM_BLOCKS; i += 256)
        s += partials[i];

    for (int o = 32; o > 0; o >>= 1)
        s += __shfl_down(s, o, 64);

    __shared__ float wsum[4];
    int lane = tid & 63;
    int wid  = tid >> 6;
    if (lane == 0) wsum[wid] = s;
    __syncthreads();
    if (tid == 0)
        out[0] = (wsum[0] + wsum[1] + wsum[2] + wsum[3])
               * (1.0f / ((float)N_ROWS * (float)D_COLS));
}

extern "C" void kernel_launch(void* const* d_in, const int* in_sizes, int n_in,
                              void* d_out, int out_size, void* d_ws, size_t ws_size,
                              hipStream_t stream) {
    const float* feats = (const float*)d_in[0];
    const int* labels  = (const int*)d_in[1];
    const int* cams    = (const int*)d_in[2];
    float* out = (float*)d_out;

    // ws layout: counts[NUM_SEG] | lists[NUM_SEG*MAXPER] | partials[NUM_BLOCKS]
    int* counts     = (int*)d_ws;
    int* lists      = counts + NUM_SEG;
    float* partials = (float*)(lists + NUM_SEG * MAXPER);

    hipMemsetAsync(counts, 0, NUM_SEG * sizeof(int), stream);   // only counts need zeroing

    build_lists_kernel<<<(N_ROWS + 255) / 256, 256, 0, stream>>>(labels, cams, counts, lists);
    group_loss_kernel<<<NUM_BLOCKS, 256, 0, stream>>>(feats, counts, lists, partials);
    reduce_kernel<<<1, 256, 0, stream>>>(partials, out);
}